// Round 4
// baseline (1609.260 us; speedup 1.0000x reference)
//
#include <hip/hip_runtime.h>

typedef __attribute__((ext_vector_type(8))) short bf16x8;
typedef __attribute__((ext_vector_type(4))) float f32x4;

#define BDIM 32768
#define DDIM 2048
#define HNUM 16
#define HD   128

// ---------- helpers ----------
__device__ inline short f2bf(float f) {
    union { float f; unsigned u; } v; v.f = f;
    unsigned r = v.u + 0x7FFFu + ((v.u >> 16) & 1u);   // round-to-nearest-even
    return (short)(r >> 16);
}
__device__ inline float bf2f(short s) {
    union { unsigned u; float f; } v; v.u = ((unsigned)(unsigned short)s) << 16; return v.f;
}

__device__ inline void load_lds16(const void* g, void* l) {
    __builtin_amdgcn_global_load_lds(
        (const __attribute__((address_space(1))) void*)g,
        (__attribute__((address_space(3))) void*)l, 16, 0, 0);
}

#define VMCNT(n) asm volatile("s_waitcnt vmcnt(" #n ")" ::: "memory")
#define LGKM0    do { asm volatile("s_waitcnt lgkmcnt(0)" ::: "memory"); __builtin_amdgcn_sched_barrier(0); } while (0)
#define BAR      __builtin_amdgcn_s_barrier()
#define SP1      __builtin_amdgcn_s_setprio(1)
#define SP0      __builtin_amdgcn_s_setprio(0)

// ---------- fp32 -> bf16 convert ----------
__global__ __launch_bounds__(256)
void cvt1(const float* __restrict__ in, short* __restrict__ out, int n8)
{
    int idx = blockIdx.x * 256 + threadIdx.x;
    int stride = gridDim.x * 256;
    for (int ch = idx; ch < n8; ch += stride) {
        const float4* p = (const float4*)(in + (size_t)ch * 8);
        float4 x0 = p[0], x1 = p[1];
        union { bf16x8 v; short s[8]; } o;
        o.s[0] = f2bf(x0.x); o.s[1] = f2bf(x0.y); o.s[2] = f2bf(x0.z); o.s[3] = f2bf(x0.w);
        o.s[4] = f2bf(x1.x); o.s[5] = f2bf(x1.y); o.s[6] = f2bf(x1.z); o.s[7] = f2bf(x1.w);
        *(bf16x8*)(out + (size_t)ch * 8) = o.v;
    }
}

// ---------- weight transpose + convert: W[K][N] fp32 -> Wt[N][K] bf16 ----------
__global__ __launch_bounds__(256)
void wtrans(const float* __restrict__ w0, const float* __restrict__ w1,
            const float* __restrict__ w2, const float* __restrict__ w3,
            short* __restrict__ o0, short* __restrict__ o1,
            short* __restrict__ o2, short* __restrict__ o3)
{
    const float* W = blockIdx.z == 0 ? w0 : blockIdx.z == 1 ? w1 : blockIdx.z == 2 ? w2 : w3;
    short*       O = blockIdx.z == 0 ? o0 : blockIdx.z == 1 ? o1 : blockIdx.z == 2 ? o2 : o3;
    __shared__ float t[32][33];
    int bx = blockIdx.x * 32;   // n
    int by = blockIdx.y * 32;   // k
    int tx = threadIdx.x, ty = threadIdx.y;  // 32 x 8
    #pragma unroll
    for (int r = 0; r < 4; ++r)
        t[ty + 8*r][tx] = W[(size_t)(by + ty + 8*r) * DDIM + bx + tx];
    __syncthreads();
    #pragma unroll
    for (int r = 0; r < 4; ++r)
        O[(size_t)(bx + ty + 8*r) * DDIM + by + tx] = f2bf(t[tx][ty + 8*r]);
}

// ---------- 256x256 8-wave 8-phase bf16 GEMM (m201-template schedule) ----------
// C[M,N] = A[M,K] * Bt[N,K]^T + bias.  MODE 0: bf16 out. MODE 1: f32 out + bf16 resid.
// LDS: buf0 = even K-tiles, buf1 = odd K-tiles (static). Per iteration: consume
// tiles 2j (ph0-3) and 2j+1 (ph4-7); stage one half-tile per phase, each slot
// overwritten exactly one phase after its last ds_read. vmcnt(6) ONLY at ph3/ph7.

template<int MH, int NH>
__device__ inline void quadf(f32x4 (&acc)[8][4], bf16x8 (&a)[4][2], bf16x8 (&b)[2][2])
{
    #pragma unroll
    for (int kk = 0; kk < 2; ++kk)
        #pragma unroll
        for (int mi = 0; mi < 4; ++mi)
            #pragma unroll
            for (int ni = 0; ni < 2; ++ni)
                acc[MH*4 + mi][NH*2 + ni] = __builtin_amdgcn_mfma_f32_16x16x32_bf16(
                    a[mi][kk], b[ni][kk], acc[MH*4 + mi][NH*2 + ni], 0, 0, 0);
}

template<int MODE>
__global__ __launch_bounds__(512)
void gemm8(const short* __restrict__ A, const short* __restrict__ Bt,
           const float* __restrict__ bias, const short* __restrict__ resid,
           short* __restrict__ Cb, float* __restrict__ Cf, int M, int N, int K)
{
    __shared__ __align__(16) short lds[2][2][256 * 64];
    const int tid = threadIdx.x;

    const int ntn = N >> 8;
    const int nwg = (M >> 8) * ntn;
    const int cpx = nwg >> 3;                       // nwg % 8 == 0
    const int wg  = ((int)blockIdx.x & 7) * cpx + ((int)blockIdx.x >> 3);
    const int tm  = wg / ntn, tn = wg % ntn;

    const int wave = tid >> 6, lane = tid & 63;
    const int wm = wave >> 2, wn = wave & 3;        // 2 x 4 wave grid, each 128x64 out
    const int lrow = lane & 15, lgrp = lane >> 4;

    const short* Ab = A  + (size_t)tm * 256 * K;
    const short* Bb = Bt + (size_t)tn * 256 * K;

    // staging: one half-tile = 128 rows x 64 cols bf16 = 2 x gload_lds16 per thread
    auto stageA = [&](int buf, int mh, int k0) {
        short* dst = &lds[buf][0][0];
        #pragma unroll
        for (int l = 0; l < 2; ++l) {
            int ci = l * 512 + tid;
            int rs = ci >> 3, c = ci & 7;
            int lr = ((rs >> 6) << 7) | (mh << 6) | (rs & 63);   // rows with bit6==mh
            int cg = c ^ (lr & 7);                               // inverse swizzle on source
            load_lds16(Ab + (size_t)lr * K + k0 + cg * 8, dst + lr * 64 + c * 8);
        }
    };
    auto stageB = [&](int buf, int nh, int k0) {
        short* dst = &lds[buf][1][0];
        #pragma unroll
        for (int l = 0; l < 2; ++l) {
            int ci = l * 512 + tid;
            int rs = ci >> 3, c = ci & 7;
            int lr = ((rs >> 5) << 6) | (nh << 5) | (rs & 31);   // rows with bit5==nh
            int cg = c ^ (lr & 7);
            load_lds16(Bb + (size_t)lr * K + k0 + cg * 8, dst + lr * 64 + c * 8);
        }
    };

    bf16x8 a[4][2], b0[2][2], b1[2][2];
    const int sw0 = ((0 + lgrp) ^ (lrow & 7)) * 8;   // k-chunk swizzled, kk=0
    const int sw1 = ((4 + lgrp) ^ (lrow & 7)) * 8;   // kk=1

    auto readA = [&](int buf, int mh) {
        const short* s = &lds[buf][0][0];
        int base = (wm * 128 + mh * 64 + lrow) * 64;
        #pragma unroll
        for (int mi = 0; mi < 4; ++mi) {
            a[mi][0] = *(const bf16x8*)&s[base + mi * 16 * 64 + sw0];
            a[mi][1] = *(const bf16x8*)&s[base + mi * 16 * 64 + sw1];
        }
    };
    auto readB = [&](int buf, int nh, bf16x8 (&b)[2][2]) {
        const short* s = &lds[buf][1][0];
        int base = (wn * 64 + nh * 32 + lrow) * 64;
        #pragma unroll
        for (int ni = 0; ni < 2; ++ni) {
            b[ni][0] = *(const bf16x8*)&s[base + ni * 16 * 64 + sw0];
            b[ni][1] = *(const bf16x8*)&s[base + ni * 16 * 64 + sw1];
        }
    };

    f32x4 acc[8][4] = {};

    // prologue: tiles 0 (buf0) + 1 (buf1) minus A1(1); leave 3 half-tiles in flight
    stageA(0, 0, 0); stageB(0, 0, 0); stageB(0, 1, 0); stageA(0, 1, 0);
    stageA(1, 0, 64); stageB(1, 0, 64); stageB(1, 1, 64);
    VMCNT(6); BAR;

    const int NT = K >> 6;            // K-tiles (even)
    const int NP = (NT >> 1) - 1;     // full 2-tile iterations
    for (int j = 0; j < NP; ++j) {
        const int ka = (2 * j + 1) << 6;
        const int kb = (2 * j + 2) << 6;
        const int kc = (2 * j + 3) << 6;
        // ph0: quad(0,0) on tile 2j | stage A1(2j+1)
        readA(0, 0); readB(0, 0, b0);
        stageA(1, 1, ka);
        BAR; LGKM0;
        SP1; quadf<0,0>(acc, a, b0); SP0;
        BAR;
        // ph1: quad(0,1) | stage A0(2j+2)
        readB(0, 1, b1);
        stageA(0, 0, kb);
        BAR; LGKM0;
        SP1; quadf<0,1>(acc, a, b1); SP0;
        BAR;
        // ph2: quad(1,0) | stage B0(2j+2)
        readA(0, 1);
        stageB(0, 0, kb);
        BAR; LGKM0;
        SP1; quadf<1,0>(acc, a, b0); SP0;
        BAR;
        // ph3: quad(1,1) | stage B1(2j+2) | vmcnt(6)
        stageB(0, 1, kb);
        VMCNT(6); BAR;
        SP1; quadf<1,1>(acc, a, b1); SP0;
        BAR;
        // ph4: quad(0,0) on tile 2j+1 | stage A1(2j+2)
        readA(1, 0); readB(1, 0, b0);
        stageA(0, 1, kb);
        BAR; LGKM0;
        SP1; quadf<0,0>(acc, a, b0); SP0;
        BAR;
        // ph5: quad(0,1) | stage A0(2j+3)
        readB(1, 1, b1);
        stageA(1, 0, kc);
        BAR; LGKM0;
        SP1; quadf<0,1>(acc, a, b1); SP0;
        BAR;
        // ph6: quad(1,0) | stage B0(2j+3)
        readA(1, 1);
        stageB(1, 0, kc);
        BAR; LGKM0;
        SP1; quadf<1,0>(acc, a, b0); SP0;
        BAR;
        // ph7: quad(1,1) | stage B1(2j+3) | vmcnt(6)
        stageB(1, 1, kc);
        VMCNT(6); BAR;
        SP1; quadf<1,1>(acc, a, b1); SP0;
        BAR;
    }

    // epilogue: consume tiles NT-2 (buf0), NT-1 (buf1); drain 4 -> 2 -> 0
    {
        const int ke = (NT - 1) << 6;
        // ph0: stage the last half-tile A1(NT-1)
        readA(0, 0); readB(0, 0, b0);
        stageA(1, 1, ke);
        BAR; LGKM0;
        SP1; quadf<0,0>(acc, a, b0); SP0;
        BAR;
        // ph1
        readB(0, 1, b1);
        BAR; LGKM0;
        SP1; quadf<0,1>(acc, a, b1); SP0;
        BAR;
        // ph2
        readA(0, 1);
        BAR; LGKM0;
        SP1; quadf<1,0>(acc, a, b0); SP0;
        BAR;
        // ph3: vmcnt(4) -> A0,B0(NT-1) ready for ph4 reads
        VMCNT(4); BAR;
        SP1; quadf<1,1>(acc, a, b1); SP0;
        BAR;
        // ph4: vmcnt(2) -> B1(NT-1) ready for ph5
        readA(1, 0); readB(1, 0, b0);
        VMCNT(2); BAR; LGKM0;
        SP1; quadf<0,0>(acc, a, b0); SP0;
        BAR;
        // ph5: vmcnt(0) -> A1(NT-1) ready for ph6
        readB(1, 1, b1);
        VMCNT(0); BAR; LGKM0;
        SP1; quadf<0,1>(acc, a, b1); SP0;
        BAR;
        // ph6 + ph7 (register-resident)
        readA(1, 1);
        LGKM0;
        quadf<1,0>(acc, a, b0);
        quadf<1,1>(acc, a, b1);
    }

    // C write
    #pragma unroll
    for (int m = 0; m < 8; ++m) {
        #pragma unroll
        for (int n = 0; n < 4; ++n) {
            const int col = tn * 256 + wn * 64 + n * 16 + lrow;
            const float bv = bias[col];
            #pragma unroll
            for (int r = 0; r < 4; ++r) {
                const int row = tm * 256 + wm * 128 + m * 16 + lgrp * 4 + r;
                float v = acc[m][n][r] + bv;
                if (MODE == 0) {
                    Cb[(size_t)row * N + col] = f2bf(v);
                } else {
                    v += bf2f(resid[(size_t)row * N + col]);
                    Cf[(size_t)row * N + col] = v;
                }
            }
        }
    }
}

// ---------- per-sample 16-head cosine attention (bf16 in), transposed bf16 out ----------
#define PAD 132

__global__ __launch_bounds__(256)
void attn(const short* __restrict__ qp, const short* __restrict__ kp,
          const short* __restrict__ vp, short* __restrict__ ot)
{
    __shared__ __align__(16) float qs[HNUM * PAD];
    __shared__ __align__(16) float ks[HNUM * PAD];
    __shared__ __align__(16) float vs[HNUM * PAD];
    __shared__ float rq[HNUM], rk[HNUM], sm[HNUM * 17];

    const int b = blockIdx.x;
    const int tid = threadIdx.x;
    const short* qr = qp + (size_t)b * DDIM;
    const short* kr = kp + (size_t)b * DDIM;
    const short* vr = vp + (size_t)b * DDIM;

    {
        int e = tid * 8;
        int h = e >> 7, d = e & 127;
        union { bf16x8 v; short s[8]; } u;
        float4 f0, f1;
        u.v = *(const bf16x8*)(qr + e);
        f0.x = bf2f(u.s[0]); f0.y = bf2f(u.s[1]); f0.z = bf2f(u.s[2]); f0.w = bf2f(u.s[3]);
        f1.x = bf2f(u.s[4]); f1.y = bf2f(u.s[5]); f1.z = bf2f(u.s[6]); f1.w = bf2f(u.s[7]);
        *(float4*)&qs[h * PAD + d] = f0; *(float4*)&qs[h * PAD + d + 4] = f1;
        u.v = *(const bf16x8*)(kr + e);
        f0.x = bf2f(u.s[0]); f0.y = bf2f(u.s[1]); f0.z = bf2f(u.s[2]); f0.w = bf2f(u.s[3]);
        f1.x = bf2f(u.s[4]); f1.y = bf2f(u.s[5]); f1.z = bf2f(u.s[6]); f1.w = bf2f(u.s[7]);
        *(float4*)&ks[h * PAD + d] = f0; *(float4*)&ks[h * PAD + d + 4] = f1;
        u.v = *(const bf16x8*)(vr + e);
        f0.x = bf2f(u.s[0]); f0.y = bf2f(u.s[1]); f0.z = bf2f(u.s[2]); f0.w = bf2f(u.s[3]);
        f1.x = bf2f(u.s[4]); f1.y = bf2f(u.s[5]); f1.z = bf2f(u.s[6]); f1.w = bf2f(u.s[7]);
        *(float4*)&vs[h * PAD + d] = f0; *(float4*)&vs[h * PAD + d + 4] = f1;
    }
    __syncthreads();

    {
        int h = tid >> 4, p = tid & 15;
        float sq = 0.f, sk = 0.f;
        #pragma unroll
        for (int j = 0; j < 8; ++j) {
            float x = qs[h * PAD + p + 16 * j]; sq += x * x;
            float y = ks[h * PAD + p + 16 * j]; sk += y * y;
        }
        #pragma unroll
        for (int m = 1; m < 16; m <<= 1) {
            sq += __shfl_xor(sq, m);
            sk += __shfl_xor(sk, m);
        }
        if (p == 0) { rq[h] = rsqrtf(sq); rk[h] = rsqrtf(sk); }
    }
    __syncthreads();

    {
        int h = tid >> 4, g = tid & 15;
        float dot = 0.f;
        #pragma unroll
        for (int d = 0; d < HD; d += 4) {
            float4 q4 = *(const float4*)&qs[h * PAD + d];
            float4 k4 = *(const float4*)&ks[g * PAD + d];
            dot += q4.x * k4.x + q4.y * k4.y + q4.z * k4.z + q4.w * k4.w;
        }
        sm[h * 17 + g] = dot * rq[h] * rk[g] * (1.0f / 128.0f);
    }
    __syncthreads();

    {
        int h = tid & 15, u = tid >> 4;
        float o[8] = {};
        #pragma unroll
        for (int g = 0; g < 16; ++g) {
            float s = sm[h * 17 + g];
            #pragma unroll
            for (int i = 0; i < 8; ++i)
                o[i] = fmaf(s, vs[g * PAD + u + 16 * i], o[i]);
        }
        #pragma unroll
        for (int i = 0; i < 8; ++i)
            ot[(size_t)b * DDIM + u * 16 + 256 * i + h] = f2bf(o[i]);
    }
}

// ---------- in-place row LayerNorm ----------
__global__ __launch_bounds__(256)
void lnorm(float* __restrict__ x, const float* __restrict__ gamma, const float* __restrict__ beta)
{
    const int row = blockIdx.x;
    const int tid = threadIdx.x;
    float* xr = x + (size_t)row * DDIM;

    float4 v0 = *(const float4*)(xr + tid * 4);
    float4 v1 = *(const float4*)(xr + 1024 + tid * 4);
    float s  = v0.x + v0.y + v0.z + v0.w + v1.x + v1.y + v1.z + v1.w;
    float s2 = v0.x*v0.x + v0.y*v0.y + v0.z*v0.z + v0.w*v0.w
             + v1.x*v1.x + v1.y*v1.y + v1.z*v1.z + v1.w*v1.w;

    #pragma unroll
    for (int m = 1; m < 64; m <<= 1) {
        s  += __shfl_xor(s, m);
        s2 += __shfl_xor(s2, m);
    }
    __shared__ float ws1[4], ws2[4];
    if ((tid & 63) == 0) { ws1[tid >> 6] = s; ws2[tid >> 6] = s2; }
    __syncthreads();
    s  = ws1[0] + ws1[1] + ws1[2] + ws1[3];
    s2 = ws2[0] + ws2[1] + ws2[2] + ws2[3];

    const float mu  = s * (1.0f / DDIM);
    const float var = s2 * (1.0f / DDIM) - mu * mu;
    const float rstd = rsqrtf(var + 1e-5f);

    float4 g0 = *(const float4*)(gamma + tid * 4);
    float4 g1 = *(const float4*)(gamma + 1024 + tid * 4);
    float4 b0 = *(const float4*)(beta + tid * 4);
    float4 b1 = *(const float4*)(beta + 1024 + tid * 4);

    v0.x = (v0.x - mu) * rstd * g0.x + b0.x;
    v0.y = (v0.y - mu) * rstd * g0.y + b0.y;
    v0.z = (v0.z - mu) * rstd * g0.z + b0.z;
    v0.w = (v0.w - mu) * rstd * g0.w + b0.w;
    v1.x = (v1.x - mu) * rstd * g1.x + b1.x;
    v1.y = (v1.y - mu) * rstd * g1.y + b1.y;
    v1.z = (v1.z - mu) * rstd * g1.z + b1.z;
    v1.w = (v1.w - mu) * rstd * g1.w + b1.w;

    *(float4*)(xr + tid * 4) = v0;
    *(float4*)(xr + 1024 + tid * 4) = v1;
}

// ---------- launch ----------
extern "C" void kernel_launch(void* const* d_in, const int* in_sizes, int n_in,
                              void* d_out, int out_size, void* d_ws, size_t ws_size,
                              hipStream_t stream)
{
    const float* q     = (const float*)d_in[0];
    const float* k     = (const float*)d_in[1];
    const float* v     = (const float*)d_in[2];
    const float* Wq    = (const float*)d_in[3];
    const float* bq    = (const float*)d_in[4];
    const float* Wk    = (const float*)d_in[5];
    const float* bk    = (const float*)d_in[6];
    const float* Wv    = (const float*)d_in[7];
    const float* bv    = (const float*)d_in[8];
    const float* Wo    = (const float*)d_in[9];
    const float* bo    = (const float*)d_in[10];
    const float* gamma = (const float*)d_in[11];
    const float* beta  = (const float*)d_in[12];

    const size_t BD = (size_t)BDIM * DDIM;
    char* ws = (char*)d_ws;
    size_t off = 0;
    auto alloc = [&](size_t bytes) { void* p = ws + off; off += (bytes + 255) & ~(size_t)255; return p; };

    short* Wqt = (short*)alloc((size_t)DDIM * DDIM * 2);
    short* Wkt = (short*)alloc((size_t)DDIM * DDIM * 2);
    short* Wvt = (short*)alloc((size_t)DDIM * DDIM * 2);
    short* Wot = (short*)alloc((size_t)DDIM * DDIM * 2);
    short* xb  = (short*)alloc(BD * 2);   // bf16 conv buffer (q/k/v in turn), then attn out
    short* qpb = (short*)alloc(BD * 2);   // bf16 q-projection (attn input + residual)
    short* kpb = (short*)alloc(BD * 2);
    short* vpb = (short*)alloc(BD * 2);
    float* xout = (float*)d_out;

    wtrans<<<dim3(DDIM / 32, DDIM / 32, 4), dim3(32, 8), 0, stream>>>(Wq, Wk, Wv, Wo, Wqt, Wkt, Wvt, Wot);

    const int grid = (BDIM / 256) * (DDIM / 256);   // 1024
    const int n8 = (int)(BD / 8);

    cvt1<<<4096, 256, 0, stream>>>(q, xb, n8);
    gemm8<0><<<grid, 512, 0, stream>>>(xb, Wqt, bq, nullptr, qpb, nullptr, BDIM, DDIM, DDIM);
    cvt1<<<4096, 256, 0, stream>>>(k, xb, n8);
    gemm8<0><<<grid, 512, 0, stream>>>(xb, Wkt, bk, nullptr, kpb, nullptr, BDIM, DDIM, DDIM);
    cvt1<<<4096, 256, 0, stream>>>(v, xb, n8);
    gemm8<0><<<grid, 512, 0, stream>>>(xb, Wvt, bv, nullptr, vpb, nullptr, BDIM, DDIM, DDIM);

    attn<<<BDIM, 256, 0, stream>>>(qpb, kpb, vpb, xb);

    gemm8<1><<<grid, 512, 0, stream>>>(xb, Wot, bo, qpb, nullptr, xout, BDIM, DDIM, DDIM);

    lnorm<<<BDIM, 256, 0, stream>>>(xout, gamma, beta);
}

// Round 5
// 1512.339 us; speedup vs baseline: 1.0641x; 1.0641x over previous
//
#include <hip/hip_runtime.h>

typedef __attribute__((ext_vector_type(8))) short bf16x8;
typedef __attribute__((ext_vector_type(4))) float f32x4;

#define BDIM 32768
#define DDIM 2048
#define HNUM 16
#define HD   128

// ---------- helpers ----------
__device__ inline short f2bf(float f) {
    union { float f; unsigned u; } v; v.f = f;
    unsigned r = v.u + 0x7FFFu + ((v.u >> 16) & 1u);   // round-to-nearest-even
    return (short)(r >> 16);
}
__device__ inline float bf2f(short s) {
    union { unsigned u; float f; } v; v.u = ((unsigned)(unsigned short)s) << 16; return v.f;
}

__device__ inline void load_lds16(const void* g, void* l) {
    __builtin_amdgcn_global_load_lds(
        (const __attribute__((address_space(1))) void*)g,
        (__attribute__((address_space(3))) void*)l, 16, 0, 0);
}

#define VMCNT(n) asm volatile("s_waitcnt vmcnt(" #n ")" ::: "memory")
#define LGKM0    do { asm volatile("s_waitcnt lgkmcnt(0)" ::: "memory"); __builtin_amdgcn_sched_barrier(0); } while (0)
#define BAR      __builtin_amdgcn_s_barrier()
#define SP1      __builtin_amdgcn_s_setprio(1)
#define SP0      __builtin_amdgcn_s_setprio(0)

// ---------- fp32 -> bf16 convert ----------
__global__ __launch_bounds__(256)
void cvt1(const float* __restrict__ in, short* __restrict__ out, int n8)
{
    int idx = blockIdx.x * 256 + threadIdx.x;
    int stride = gridDim.x * 256;
    for (int ch = idx; ch < n8; ch += stride) {
        const float4* p = (const float4*)(in + (size_t)ch * 8);
        float4 x0 = p[0], x1 = p[1];
        union { bf16x8 v; short s[8]; } o;
        o.s[0] = f2bf(x0.x); o.s[1] = f2bf(x0.y); o.s[2] = f2bf(x0.z); o.s[3] = f2bf(x0.w);
        o.s[4] = f2bf(x1.x); o.s[5] = f2bf(x1.y); o.s[6] = f2bf(x1.z); o.s[7] = f2bf(x1.w);
        *(bf16x8*)(out + (size_t)ch * 8) = o.v;
    }
}

// ---------- weight transpose + convert: W[K][N] fp32 -> Wt[N][K] bf16 ----------
__global__ __launch_bounds__(256)
void wtrans(const float* __restrict__ w0, const float* __restrict__ w1,
            const float* __restrict__ w2, const float* __restrict__ w3,
            short* __restrict__ o0, short* __restrict__ o1,
            short* __restrict__ o2, short* __restrict__ o3)
{
    const float* W = blockIdx.z == 0 ? w0 : blockIdx.z == 1 ? w1 : blockIdx.z == 2 ? w2 : w3;
    short*       O = blockIdx.z == 0 ? o0 : blockIdx.z == 1 ? o1 : blockIdx.z == 2 ? o2 : o3;
    __shared__ float t[32][33];
    int bx = blockIdx.x * 32;   // n
    int by = blockIdx.y * 32;   // k
    int tx = threadIdx.x, ty = threadIdx.y;  // 32 x 8
    #pragma unroll
    for (int r = 0; r < 4; ++r)
        t[ty + 8*r][tx] = W[(size_t)(by + ty + 8*r) * DDIM + bx + tx];
    __syncthreads();
    #pragma unroll
    for (int r = 0; r < 4; ++r)
        O[(size_t)(bx + ty + 8*r) * DDIM + by + tx] = f2bf(t[tx][ty + 8*r]);
}

// ---------- 256x256 8-wave 8-phase bf16 GEMM, hoisted addressing ----------
// Fixed shape: M=32768, N=2048, K=2048 (constexpr). C = A * Bt^T + bias.
// MODE 0: bf16 out. MODE 1: f32 out + bf16 resid.
// Schedule: buf0=even K-tiles, buf1=odd. Per 8-phase iteration consume tiles
// 2j,2j+1; one half-tile stage per phase; vmcnt(6) at ph3/ph7 only; fragment
// ds_reads issued one phase EARLY (after MFMA, pre-barrier) so LDS drain
// overlaps barriers + stage issue.

template<int MH, int NH>
__device__ inline void quadf(f32x4 (&acc)[8][4], bf16x8 (&a)[4][2], bf16x8 (&b)[2][2])
{
    #pragma unroll
    for (int kk = 0; kk < 2; ++kk)
        #pragma unroll
        for (int mi = 0; mi < 4; ++mi)
            #pragma unroll
            for (int ni = 0; ni < 2; ++ni)
                acc[MH*4 + mi][NH*2 + ni] = __builtin_amdgcn_mfma_f32_16x16x32_bf16(
                    a[mi][kk], b[ni][kk], acc[MH*4 + mi][NH*2 + ni], 0, 0, 0);
}

template<int MODE>
__global__ __launch_bounds__(512)
void gemm8(const short* __restrict__ A, const short* __restrict__ Bt,
           const float* __restrict__ bias, const short* __restrict__ resid,
           short* __restrict__ Cb, float* __restrict__ Cf)
{
    constexpr int K = 2048, N = 2048;
    constexpr int NT = K >> 6;            // 32 K-tiles
    constexpr int NP = (NT >> 1) - 1;     // 15 full iterations
    __shared__ __align__(16) short lds[2][2][256 * 64];
    const int tid = threadIdx.x;

    constexpr int ntn = N >> 8;           // 8
    constexpr int cpx = 128;              // (M>>8)*ntn / 8 = 1024/8
    const int wg  = ((int)blockIdx.x & 7) * cpx + ((int)blockIdx.x >> 3);
    const int tm  = wg >> 3, tn = wg & 7;

    const int wave = tid >> 6, lane = tid & 63;
    const int wm = wave >> 2, wn = wave & 3;        // 2 x 4 wave grid, 128x64 out each
    const int lrow = lane & 15, lgrp = lane >> 4;

    const short* Ab = A  + (size_t)tm * 256 * K;
    const short* Bb = Bt + (size_t)tn * 256 * K;

    // ---- staging streams: precomputed pointers + LDS offsets ----
    const int r0 = tid >> 3, c0 = tid & 7;
    const int cg = c0 ^ (r0 & 7);                   // inverse swizzle on source
    constexpr size_t DL  = (size_t)128 * K;         // l=1 global delta (elems)
    constexpr int    DLD = 128 * 64;                // l=1 LDS delta (elems)
    const int rB = ((r0 >> 5) << 6) | (r0 & 31);    // B row, nh=0, l=0

    const short* pA0 = Ab + (size_t)r0 * K + cg * 8;
    const short* pA1 = Ab + (size_t)(64 + r0) * K + cg * 8;
    const short* pB0 = Bb + (size_t)rB * K + cg * 8;
    const short* pB1 = Bb + (size_t)(rB + 32) * K + cg * 8;

    short* base = &lds[0][0][0];
    int oA0 = r0 * 64 + c0 * 8;                     // into [buf][0]
    int oA1 = (64 + r0) * 64 + c0 * 8;
    int oB0 = 16384 + rB * 64 + c0 * 8;             // into [buf][1]
    int oB1 = 16384 + (rB + 32) * 64 + c0 * 8;

    auto stA0 = [&]{ load_lds16(pA0, base + oA0); load_lds16(pA0 + DL, base + oA0 + DLD); pA0 += 64; oA0 ^= 32768; };
    auto stA1 = [&]{ load_lds16(pA1, base + oA1); load_lds16(pA1 + DL, base + oA1 + DLD); pA1 += 64; oA1 ^= 32768; };
    auto stB0 = [&]{ load_lds16(pB0, base + oB0); load_lds16(pB0 + DL, base + oB0 + DLD); pB0 += 64; oB0 ^= 32768; };
    auto stB1 = [&]{ load_lds16(pB1, base + oB1); load_lds16(pB1 + DL, base + oB1 + DLD); pB1 += 64; oB1 ^= 32768; };

    // ---- fragment reads ----
    bf16x8 a[4][2], b0[2][2], b1[2][2];
    const int sw0 = (lgrp ^ (lrow & 7)) * 8;
    const int sw1 = ((4 + lgrp) ^ (lrow & 7)) * 8;

    auto readA = [&](int buf, int mh) {
        const short* s = &lds[buf][0][0];
        int bb = (wm * 128 + mh * 64 + lrow) * 64;
        #pragma unroll
        for (int mi = 0; mi < 4; ++mi) {
            a[mi][0] = *(const bf16x8*)&s[bb + mi * 1024 + sw0];
            a[mi][1] = *(const bf16x8*)&s[bb + mi * 1024 + sw1];
        }
    };
    auto readB = [&](int buf, int nh, bf16x8 (&b)[2][2]) {
        const short* s = &lds[buf][1][0];
        int bb = (wn * 64 + nh * 32 + lrow) * 64;
        #pragma unroll
        for (int ni = 0; ni < 2; ++ni) {
            b[ni][0] = *(const bf16x8*)&s[bb + ni * 1024 + sw0];
            b[ni][1] = *(const bf16x8*)&s[bb + ni * 1024 + sw1];
        }
    };

    f32x4 acc[8][4] = {};

    // prologue: tile0 (buf0) full + tile1 (buf1) minus A1; then prime ph0 reads
    stA0(); stB0(); stB1(); stA1();      // tile 0 -> buf0
    stA0(); stB0(); stB1();              // tile 1 -> buf1 (A0,B0,B1)
    VMCNT(6); BAR;
    readA(0, 0); readB(0, 0, b0);

    for (int j = 0; j < NP; ++j) {
        // ph0: stage A1(2j+1)->buf1
        stA1();
        BAR; LGKM0;
        SP1; quadf<0,0>(acc, a, b0); SP0;
        readB(0, 1, b1);
        BAR;
        // ph1: stage A0(2j+2)->buf0
        stA0();
        BAR; LGKM0;
        SP1; quadf<0,1>(acc, a, b1); SP0;
        readA(0, 1);
        BAR;
        // ph2: stage B0(2j+2)->buf0
        stB0();
        BAR; LGKM0;
        SP1; quadf<1,0>(acc, a, b0); SP0;
        BAR;
        // ph3: stage B1(2j+2)->buf0 | vmcnt(6) lands tile 2j+1
        stB1();
        VMCNT(6); BAR;
        SP1; quadf<1,1>(acc, a, b1); SP0;
        readA(1, 0); readB(1, 0, b0);
        BAR;
        // ph4: stage A1(2j+2)->buf0
        stA1();
        BAR; LGKM0;
        SP1; quadf<0,0>(acc, a, b0); SP0;
        readB(1, 1, b1);
        BAR;
        // ph5: stage A0(2j+3)->buf1
        stA0();
        BAR; LGKM0;
        SP1; quadf<0,1>(acc, a, b1); SP0;
        readA(1, 1);
        BAR;
        // ph6: stage B0(2j+3)->buf1
        stB0();
        BAR; LGKM0;
        SP1; quadf<1,0>(acc, a, b0); SP0;
        BAR;
        // ph7: stage B1(2j+3)->buf1 | vmcnt(6) lands tile 2j+2
        stB1();
        VMCNT(6); BAR;
        SP1; quadf<1,1>(acc, a, b1); SP0;
        readA(0, 0); readB(0, 0, b0);
        BAR;
    }

    // epilogue: tiles NT-2 (buf0), NT-1 (buf1); outstanding = A0,B0,B1(NT-1)
    // e0: stage the last half-tile A1(NT-1)->buf1
    stA1();
    BAR; LGKM0;
    SP1; quadf<0,0>(acc, a, b0); SP0;
    readB(0, 1, b1);
    BAR;
    // e1
    BAR; LGKM0;
    SP1; quadf<0,1>(acc, a, b1); SP0;
    readA(0, 1);
    BAR;
    // e2
    BAR; LGKM0;
    SP1; quadf<1,0>(acc, a, b0); SP0;
    BAR;
    // e3: vmcnt(4) lands A0,B0(NT-1)
    VMCNT(4); BAR;
    SP1; quadf<1,1>(acc, a, b1); SP0;
    readA(1, 0); readB(1, 0, b0);
    BAR;
    // e4: vmcnt(2) lands B1(NT-1)
    VMCNT(2); BAR; LGKM0;
    SP1; quadf<0,0>(acc, a, b0); SP0;
    readB(1, 1, b1);
    BAR;
    // e5: vmcnt(0) lands A1(NT-1)
    VMCNT(0); BAR; LGKM0;
    SP1; quadf<0,1>(acc, a, b1); SP0;
    readA(1, 1);
    BAR;
    // e6 + e7
    LGKM0;
    quadf<1,0>(acc, a, b0);
    quadf<1,1>(acc, a, b1);

    // C write
    #pragma unroll
    for (int m = 0; m < 8; ++m) {
        #pragma unroll
        for (int n = 0; n < 4; ++n) {
            const int col = tn * 256 + wn * 64 + n * 16 + lrow;
            const float bv = bias[col];
            #pragma unroll
            for (int r = 0; r < 4; ++r) {
                const int row = tm * 256 + wm * 128 + m * 16 + lgrp * 4 + r;
                float v = acc[m][n][r] + bv;
                if (MODE == 0) {
                    Cb[(size_t)row * N + col] = f2bf(v);
                } else {
                    v += bf2f(resid[(size_t)row * N + col]);
                    Cf[(size_t)row * N + col] = v;
                }
            }
        }
    }
}

// ---------- per-sample 16-head cosine attention (bf16 in), transposed bf16 out ----------
#define PAD 132

__global__ __launch_bounds__(256)
void attn(const short* __restrict__ qp, const short* __restrict__ kp,
          const short* __restrict__ vp, short* __restrict__ ot)
{
    __shared__ __align__(16) float qs[HNUM * PAD];
    __shared__ __align__(16) float ks[HNUM * PAD];
    __shared__ __align__(16) float vs[HNUM * PAD];
    __shared__ float rq[HNUM], rk[HNUM], sm[HNUM * 17];

    const int b = blockIdx.x;
    const int tid = threadIdx.x;
    const short* qr = qp + (size_t)b * DDIM;
    const short* kr = kp + (size_t)b * DDIM;
    const short* vr = vp + (size_t)b * DDIM;

    {
        int e = tid * 8;
        int h = e >> 7, d = e & 127;
        union { bf16x8 v; short s[8]; } u;
        float4 f0, f1;
        u.v = *(const bf16x8*)(qr + e);
        f0.x = bf2f(u.s[0]); f0.y = bf2f(u.s[1]); f0.z = bf2f(u.s[2]); f0.w = bf2f(u.s[3]);
        f1.x = bf2f(u.s[4]); f1.y = bf2f(u.s[5]); f1.z = bf2f(u.s[6]); f1.w = bf2f(u.s[7]);
        *(float4*)&qs[h * PAD + d] = f0; *(float4*)&qs[h * PAD + d + 4] = f1;
        u.v = *(const bf16x8*)(kr + e);
        f0.x = bf2f(u.s[0]); f0.y = bf2f(u.s[1]); f0.z = bf2f(u.s[2]); f0.w = bf2f(u.s[3]);
        f1.x = bf2f(u.s[4]); f1.y = bf2f(u.s[5]); f1.z = bf2f(u.s[6]); f1.w = bf2f(u.s[7]);
        *(float4*)&ks[h * PAD + d] = f0; *(float4*)&ks[h * PAD + d + 4] = f1;
        u.v = *(const bf16x8*)(vr + e);
        f0.x = bf2f(u.s[0]); f0.y = bf2f(u.s[1]); f0.z = bf2f(u.s[2]); f0.w = bf2f(u.s[3]);
        f1.x = bf2f(u.s[4]); f1.y = bf2f(u.s[5]); f1.z = bf2f(u.s[6]); f1.w = bf2f(u.s[7]);
        *(float4*)&vs[h * PAD + d] = f0; *(float4*)&vs[h * PAD + d + 4] = f1;
    }
    __syncthreads();

    {
        int h = tid >> 4, p = tid & 15;
        float sq = 0.f, sk = 0.f;
        #pragma unroll
        for (int j = 0; j < 8; ++j) {
            float x = qs[h * PAD + p + 16 * j]; sq += x * x;
            float y = ks[h * PAD + p + 16 * j]; sk += y * y;
        }
        #pragma unroll
        for (int m = 1; m < 16; m <<= 1) {
            sq += __shfl_xor(sq, m);
            sk += __shfl_xor(sk, m);
        }
        if (p == 0) { rq[h] = rsqrtf(sq); rk[h] = rsqrtf(sk); }
    }
    __syncthreads();

    {
        int h = tid >> 4, g = tid & 15;
        float dot = 0.f;
        #pragma unroll
        for (int d = 0; d < HD; d += 4) {
            float4 q4 = *(const float4*)&qs[h * PAD + d];
            float4 k4 = *(const float4*)&ks[g * PAD + d];
            dot += q4.x * k4.x + q4.y * k4.y + q4.z * k4.z + q4.w * k4.w;
        }
        sm[h * 17 + g] = dot * rq[h] * rk[g] * (1.0f / 128.0f);
    }
    __syncthreads();

    {
        int h = tid & 15, u = tid >> 4;
        float o[8] = {};
        #pragma unroll
        for (int g = 0; g < 16; ++g) {
            float s = sm[h * 17 + g];
            #pragma unroll
            for (int i = 0; i < 8; ++i)
                o[i] = fmaf(s, vs[g * PAD + u + 16 * i], o[i]);
        }
        #pragma unroll
        for (int i = 0; i < 8; ++i)
            ot[(size_t)b * DDIM + u * 16 + 256 * i + h] = f2bf(o[i]);
    }
}

// ---------- in-place row LayerNorm ----------
__global__ __launch_bounds__(256)
void lnorm(float* __restrict__ x, const float* __restrict__ gamma, const float* __restrict__ beta)
{
    const int row = blockIdx.x;
    const int tid = threadIdx.x;
    float* xr = x + (size_t)row * DDIM;

    float4 v0 = *(const float4*)(xr + tid * 4);
    float4 v1 = *(const float4*)(xr + 1024 + tid * 4);
    float s  = v0.x + v0.y + v0.z + v0.w + v1.x + v1.y + v1.z + v1.w;
    float s2 = v0.x*v0.x + v0.y*v0.y + v0.z*v0.z + v0.w*v0.w
             + v1.x*v1.x + v1.y*v1.y + v1.z*v1.z + v1.w*v1.w;

    #pragma unroll
    for (int m = 1; m < 64; m <<= 1) {
        s  += __shfl_xor(s, m);
        s2 += __shfl_xor(s2, m);
    }
    __shared__ float ws1[4], ws2[4];
    if ((tid & 63) == 0) { ws1[tid >> 6] = s; ws2[tid >> 6] = s2; }
    __syncthreads();
    s  = ws1[0] + ws1[1] + ws1[2] + ws1[3];
    s2 = ws2[0] + ws2[1] + ws2[2] + ws2[3];

    const float mu  = s * (1.0f / DDIM);
    const float var = s2 * (1.0f / DDIM) - mu * mu;
    const float rstd = rsqrtf(var + 1e-5f);

    float4 g0 = *(const float4*)(gamma + tid * 4);
    float4 g1 = *(const float4*)(gamma + 1024 + tid * 4);
    float4 b0 = *(const float4*)(beta + tid * 4);
    float4 b1 = *(const float4*)(beta + 1024 + tid * 4);

    v0.x = (v0.x - mu) * rstd * g0.x + b0.x;
    v0.y = (v0.y - mu) * rstd * g0.y + b0.y;
    v0.z = (v0.z - mu) * rstd * g0.z + b0.z;
    v0.w = (v0.w - mu) * rstd * g0.w + b0.w;
    v1.x = (v1.x - mu) * rstd * g1.x + b1.x;
    v1.y = (v1.y - mu) * rstd * g1.y + b1.y;
    v1.z = (v1.z - mu) * rstd * g1.z + b1.z;
    v1.w = (v1.w - mu) * rstd * g1.w + b1.w;

    *(float4*)(xr + tid * 4) = v0;
    *(float4*)(xr + 1024 + tid * 4) = v1;
}

// ---------- launch ----------
extern "C" void kernel_launch(void* const* d_in, const int* in_sizes, int n_in,
                              void* d_out, int out_size, void* d_ws, size_t ws_size,
                              hipStream_t stream)
{
    const float* q     = (const float*)d_in[0];
    const float* k     = (const float*)d_in[1];
    const float* v     = (const float*)d_in[2];
    const float* Wq    = (const float*)d_in[3];
    const float* bq    = (const float*)d_in[4];
    const float* Wk    = (const float*)d_in[5];
    const float* bk    = (const float*)d_in[6];
    const float* Wv    = (const float*)d_in[7];
    const float* bv    = (const float*)d_in[8];
    const float* Wo    = (const float*)d_in[9];
    const float* bo    = (const float*)d_in[10];
    const float* gamma = (const float*)d_in[11];
    const float* beta  = (const float*)d_in[12];

    const size_t BD = (size_t)BDIM * DDIM;
    char* ws = (char*)d_ws;
    size_t off = 0;
    auto alloc = [&](size_t bytes) { void* p = ws + off; off += (bytes + 255) & ~(size_t)255; return p; };

    short* Wqt = (short*)alloc((size_t)DDIM * DDIM * 2);
    short* Wkt = (short*)alloc((size_t)DDIM * DDIM * 2);
    short* Wvt = (short*)alloc((size_t)DDIM * DDIM * 2);
    short* Wot = (short*)alloc((size_t)DDIM * DDIM * 2);
    short* xb  = (short*)alloc(BD * 2);   // bf16 conv buffer (q/k/v in turn), then attn out
    short* qpb = (short*)alloc(BD * 2);   // bf16 q-projection (attn input + residual)
    short* kpb = (short*)alloc(BD * 2);
    short* vpb = (short*)alloc(BD * 2);
    float* xout = (float*)d_out;

    wtrans<<<dim3(DDIM / 32, DDIM / 32, 4), dim3(32, 8), 0, stream>>>(Wq, Wk, Wv, Wo, Wqt, Wkt, Wvt, Wot);

    const int grid = (BDIM / 256) * (DDIM / 256);   // 1024
    const int n8 = (int)(BD / 8);

    cvt1<<<4096, 256, 0, stream>>>(q, xb, n8);
    gemm8<0><<<grid, 512, 0, stream>>>(xb, Wqt, bq, nullptr, qpb, nullptr);
    cvt1<<<4096, 256, 0, stream>>>(k, xb, n8);
    gemm8<0><<<grid, 512, 0, stream>>>(xb, Wkt, bk, nullptr, kpb, nullptr);
    cvt1<<<4096, 256, 0, stream>>>(v, xb, n8);
    gemm8<0><<<grid, 512, 0, stream>>>(xb, Wvt, bv, nullptr, vpb, nullptr);

    attn<<<BDIM, 256, 0, stream>>>(qpb, kpb, vpb, xb);

    gemm8<1><<<grid, 512, 0, stream>>>(xb, Wot, bo, qpb, nullptr, xout);

    lnorm<<<BDIM, 256, 0, stream>>>(xout, gamma, beta);
}

// Round 6
// 1438.405 us; speedup vs baseline: 1.1188x; 1.0514x over previous
//
#include <hip/hip_runtime.h>

typedef __attribute__((ext_vector_type(8))) short bf16x8;
typedef __attribute__((ext_vector_type(4))) float f32x4;

#define BDIM 32768
#define DDIM 2048
#define HNUM 16
#define HD   128

// ---------- helpers ----------
__device__ inline short f2bf(float f) {
    union { float f; unsigned u; } v; v.f = f;
    unsigned r = v.u + 0x7FFFu + ((v.u >> 16) & 1u);   // round-to-nearest-even
    return (short)(r >> 16);
}
__device__ inline float bf2f(short s) {
    union { unsigned u; float f; } v; v.u = ((unsigned)(unsigned short)s) << 16; return v.f;
}

__device__ inline void load_lds16(const void* g, void* l) {
    __builtin_amdgcn_global_load_lds(
        (const __attribute__((address_space(1))) void*)g,
        (__attribute__((address_space(3))) void*)l, 16, 0, 0);
}

#define VMCNT(n) asm volatile("s_waitcnt vmcnt(" #n ")" ::: "memory")
#define BARX     do { __builtin_amdgcn_s_barrier(); __builtin_amdgcn_sched_barrier(0); } while (0)
#define SP1      __builtin_amdgcn_s_setprio(1)
#define SP0      __builtin_amdgcn_s_setprio(0)

// ---------- fp32 -> bf16 convert ----------
__global__ __launch_bounds__(256)
void cvt1(const float* __restrict__ in, short* __restrict__ out, int n8)
{
    int idx = blockIdx.x * 256 + threadIdx.x;
    int stride = gridDim.x * 256;
    for (int ch = idx; ch < n8; ch += stride) {
        const float4* p = (const float4*)(in + (size_t)ch * 8);
        float4 x0 = p[0], x1 = p[1];
        union { bf16x8 v; short s[8]; } o;
        o.s[0] = f2bf(x0.x); o.s[1] = f2bf(x0.y); o.s[2] = f2bf(x0.z); o.s[3] = f2bf(x0.w);
        o.s[4] = f2bf(x1.x); o.s[5] = f2bf(x1.y); o.s[6] = f2bf(x1.z); o.s[7] = f2bf(x1.w);
        *(bf16x8*)(out + (size_t)ch * 8) = o.v;
    }
}

// ---------- weight transpose + convert: W[K][N] fp32 -> Wt[N][K] bf16 ----------
__global__ __launch_bounds__(256)
void wtrans(const float* __restrict__ w0, const float* __restrict__ w1,
            const float* __restrict__ w2, const float* __restrict__ w3,
            short* __restrict__ o0, short* __restrict__ o1,
            short* __restrict__ o2, short* __restrict__ o3)
{
    const float* W = blockIdx.z == 0 ? w0 : blockIdx.z == 1 ? w1 : blockIdx.z == 2 ? w2 : w3;
    short*       O = blockIdx.z == 0 ? o0 : blockIdx.z == 1 ? o1 : blockIdx.z == 2 ? o2 : o3;
    __shared__ float t[32][33];
    int bx = blockIdx.x * 32;   // n
    int by = blockIdx.y * 32;   // k
    int tx = threadIdx.x, ty = threadIdx.y;  // 32 x 8
    #pragma unroll
    for (int r = 0; r < 4; ++r)
        t[ty + 8*r][tx] = W[(size_t)(by + ty + 8*r) * DDIM + bx + tx];
    __syncthreads();
    #pragma unroll
    for (int r = 0; r < 4; ++r)
        O[(size_t)(bx + ty + 8*r) * DDIM + by + tx] = f2bf(t[tx][ty + 8*r]);
}

// ---------- 256x256 8-wave 8-phase bf16 GEMM ----------
// One barrier per phase; NO asm lgkm waits -- compiler emits counted lgkmcnt
// between ds_read and MFMA (near-optimal, per m97 asm evidence). vmcnt(6) only
// at buffer-switch phases (ph0/ph4). Reads per phase: 12/4/8/0 (ph3 register-held).

template<int MH, int NH>
__device__ inline void quadf(f32x4 (&acc)[8][4], bf16x8 (&a)[4][2], bf16x8 (&b)[2][2])
{
    #pragma unroll
    for (int kk = 0; kk < 2; ++kk)
        #pragma unroll
        for (int mi = 0; mi < 4; ++mi)
            #pragma unroll
            for (int ni = 0; ni < 2; ++ni)
                acc[MH*4 + mi][NH*2 + ni] = __builtin_amdgcn_mfma_f32_16x16x32_bf16(
                    a[mi][kk], b[ni][kk], acc[MH*4 + mi][NH*2 + ni], 0, 0, 0);
}

template<int MODE>
__global__ __launch_bounds__(512)
void gemm8(const short* __restrict__ A, const short* __restrict__ Bt,
           const float* __restrict__ bias, const short* __restrict__ resid,
           short* __restrict__ Cb, float* __restrict__ Cf)
{
    constexpr int K = 2048, N = 2048;
    constexpr int NT = K >> 6;            // 32 K-tiles
    constexpr int NP = (NT >> 1) - 1;     // 15 full iterations
    __shared__ __align__(16) short lds[2][2][256 * 64];
    const int tid = threadIdx.x;

    constexpr int cpx = 128;              // 1024 wgs / 8 XCDs
    const int wg  = ((int)blockIdx.x & 7) * cpx + ((int)blockIdx.x >> 3);
    const int tm  = wg >> 3, tn = wg & 7;

    const int wave = tid >> 6, lane = tid & 63;
    const int wm = wave >> 2, wn = wave & 3;        // 2 x 4 wave grid, 128x64 out each
    const int lrow = lane & 15, lgrp = lane >> 4;

    const short* Ab = A  + (size_t)tm * 256 * K;
    const short* Bb = Bt + (size_t)tn * 256 * K;

    // ---- staging streams: precomputed pointers + LDS offsets ----
    const int r0 = tid >> 3, c0 = tid & 7;
    const int cg = c0 ^ (r0 & 7);                   // inverse swizzle on source
    constexpr size_t DL  = (size_t)128 * K;         // second-load global delta
    constexpr int    DLD = 128 * 64;                // second-load LDS delta
    const int rB = ((r0 >> 5) << 6) | (r0 & 31);    // B row for B0 stream

    const short* pA0 = Ab + (size_t)r0 * K + cg * 8;
    const short* pA1 = Ab + (size_t)(64 + r0) * K + cg * 8;
    const short* pB0 = Bb + (size_t)rB * K + cg * 8;
    const short* pB1 = Bb + (size_t)(rB + 32) * K + cg * 8;

    short* base = &lds[0][0][0];
    int oA0 = r0 * 64 + c0 * 8;                     // into [buf][0]
    int oA1 = (64 + r0) * 64 + c0 * 8;
    int oB0 = 16384 + rB * 64 + c0 * 8;             // into [buf][1]
    int oB1 = 16384 + (rB + 32) * 64 + c0 * 8;

    auto stA0 = [&]{ load_lds16(pA0, base + oA0); load_lds16(pA0 + DL, base + oA0 + DLD); pA0 += 64; oA0 ^= 32768; };
    auto stA1 = [&]{ load_lds16(pA1, base + oA1); load_lds16(pA1 + DL, base + oA1 + DLD); pA1 += 64; oA1 ^= 32768; };
    auto stB0 = [&]{ load_lds16(pB0, base + oB0); load_lds16(pB0 + DL, base + oB0 + DLD); pB0 += 64; oB0 ^= 32768; };
    auto stB1 = [&]{ load_lds16(pB1, base + oB1); load_lds16(pB1 + DL, base + oB1 + DLD); pB1 += 64; oB1 ^= 32768; };

    // ---- fragment reads (compiler inserts counted lgkmcnt before MFMA uses) ----
    bf16x8 a[4][2], b0[2][2], b1[2][2];
    const int sw0 = (lgrp ^ (lrow & 7)) * 8;
    const int sw1 = ((4 + lgrp) ^ (lrow & 7)) * 8;

    auto readA = [&](int buf, int mh) {
        const short* s = &lds[buf][0][0];
        int bb = (wm * 128 + mh * 64 + lrow) * 64;
        #pragma unroll
        for (int mi = 0; mi < 4; ++mi) {
            a[mi][0] = *(const bf16x8*)&s[bb + mi * 1024 + sw0];
            a[mi][1] = *(const bf16x8*)&s[bb + mi * 1024 + sw1];
        }
    };
    auto readB = [&](int buf, int nh, bf16x8 (&b)[2][2]) {
        const short* s = &lds[buf][1][0];
        int bb = (wn * 64 + nh * 32 + lrow) * 64;
        #pragma unroll
        for (int ni = 0; ni < 2; ++ni) {
            b[ni][0] = *(const bf16x8*)&s[bb + ni * 1024 + sw0];
            b[ni][1] = *(const bf16x8*)&s[bb + ni * 1024 + sw1];
        }
    };

    f32x4 acc[8][4] = {};

    // prologue: tile0 -> buf0 (A0,B0,B1,A1), tile1 -> buf1 (A0,B0,B1); 14 loads in flight
    stA0(); stB0(); stB1(); stA1();
    stA0(); stB0(); stB1();

    for (int j = 0; j < NP; ++j) {
        // ph0 (buf0 = tile 2j): vmcnt(6) lands tile 2j
        VMCNT(6); BARX;
        stA1();                       // A1(2j+1) -> buf1
        readA(0, 0); readB(0, 0, b0);
        SP1; quadf<0,0>(acc, a, b0); SP0;
        // ph1
        BARX;
        stA0();                       // A0(2j+2) -> buf0
        readB(0, 1, b1);
        SP1; quadf<0,1>(acc, a, b1); SP0;
        // ph2
        BARX;
        stB0();                       // B0(2j+2) -> buf0
        readA(0, 1);
        SP1; quadf<1,0>(acc, a, b0); SP0;
        // ph3 (register-held operands, no reads)
        BARX;
        stB1();                       // B1(2j+2) -> buf0
        SP1; quadf<1,1>(acc, a, b1); SP0;
        // ph4 (buf1 = tile 2j+1): vmcnt(6) lands tile 2j+1
        VMCNT(6); BARX;
        stA1();                       // A1(2j+2) -> buf0
        readA(1, 0); readB(1, 0, b0);
        SP1; quadf<0,0>(acc, a, b0); SP0;
        // ph5
        BARX;
        stA0();                       // A0(2j+3) -> buf1
        readB(1, 1, b1);
        SP1; quadf<0,1>(acc, a, b1); SP0;
        // ph6
        BARX;
        stB0();                       // B0(2j+3) -> buf1
        readA(1, 1);
        SP1; quadf<1,0>(acc, a, b0); SP0;
        // ph7
        BARX;
        stB1();                       // B1(2j+3) -> buf1
        SP1; quadf<1,1>(acc, a, b1); SP0;
    }

    // epilogue: tiles NT-2 (buf0), NT-1 (buf1); only A1(NT-1) remains to stage
    VMCNT(6); BARX;
    stA1();                           // A1(NT-1) -> buf1
    readA(0, 0); readB(0, 0, b0);
    SP1; quadf<0,0>(acc, a, b0); SP0;
    readB(0, 1, b1);
    quadf<0,1>(acc, a, b1);
    readA(0, 1);
    quadf<1,0>(acc, a, b0);
    quadf<1,1>(acc, a, b1);
    VMCNT(0); BARX;                   // tile NT-1 fully landed
    readA(1, 0); readB(1, 0, b0);
    quadf<0,0>(acc, a, b0);
    readB(1, 1, b1);
    quadf<0,1>(acc, a, b1);
    readA(1, 1);
    quadf<1,0>(acc, a, b0);
    quadf<1,1>(acc, a, b1);

    // C write
    #pragma unroll
    for (int m = 0; m < 8; ++m) {
        #pragma unroll
        for (int n = 0; n < 4; ++n) {
            const int col = tn * 256 + wn * 64 + n * 16 + lrow;
            const float bv = bias[col];
            #pragma unroll
            for (int r = 0; r < 4; ++r) {
                const int row = tm * 256 + wm * 128 + m * 16 + lgrp * 4 + r;
                float v = acc[m][n][r] + bv;
                if (MODE == 0) {
                    Cb[(size_t)row * N + col] = f2bf(v);
                } else {
                    v += bf2f(resid[(size_t)row * N + col]);
                    Cf[(size_t)row * N + col] = v;
                }
            }
        }
    }
}

// ---------- per-sample 16-head cosine attention (bf16 in), transposed bf16 out ----------
#define PAD 132

__global__ __launch_bounds__(256)
void attn(const short* __restrict__ qp, const short* __restrict__ kp,
          const short* __restrict__ vp, short* __restrict__ ot)
{
    __shared__ __align__(16) float qs[HNUM * PAD];
    __shared__ __align__(16) float ks[HNUM * PAD];
    __shared__ __align__(16) float vs[HNUM * PAD];
    __shared__ float rq[HNUM], rk[HNUM], sm[HNUM * 17];

    const int b = blockIdx.x;
    const int tid = threadIdx.x;
    const short* qr = qp + (size_t)b * DDIM;
    const short* kr = kp + (size_t)b * DDIM;
    const short* vr = vp + (size_t)b * DDIM;

    {
        int e = tid * 8;
        int h = e >> 7, d = e & 127;
        union { bf16x8 v; short s[8]; } u;
        float4 f0, f1;
        u.v = *(const bf16x8*)(qr + e);
        f0.x = bf2f(u.s[0]); f0.y = bf2f(u.s[1]); f0.z = bf2f(u.s[2]); f0.w = bf2f(u.s[3]);
        f1.x = bf2f(u.s[4]); f1.y = bf2f(u.s[5]); f1.z = bf2f(u.s[6]); f1.w = bf2f(u.s[7]);
        *(float4*)&qs[h * PAD + d] = f0; *(float4*)&qs[h * PAD + d + 4] = f1;
        u.v = *(const bf16x8*)(kr + e);
        f0.x = bf2f(u.s[0]); f0.y = bf2f(u.s[1]); f0.z = bf2f(u.s[2]); f0.w = bf2f(u.s[3]);
        f1.x = bf2f(u.s[4]); f1.y = bf2f(u.s[5]); f1.z = bf2f(u.s[6]); f1.w = bf2f(u.s[7]);
        *(float4*)&ks[h * PAD + d] = f0; *(float4*)&ks[h * PAD + d + 4] = f1;
        u.v = *(const bf16x8*)(vr + e);
        f0.x = bf2f(u.s[0]); f0.y = bf2f(u.s[1]); f0.z = bf2f(u.s[2]); f0.w = bf2f(u.s[3]);
        f1.x = bf2f(u.s[4]); f1.y = bf2f(u.s[5]); f1.z = bf2f(u.s[6]); f1.w = bf2f(u.s[7]);
        *(float4*)&vs[h * PAD + d] = f0; *(float4*)&vs[h * PAD + d + 4] = f1;
    }
    __syncthreads();

    {
        int h = tid >> 4, p = tid & 15;
        float sq = 0.f, sk = 0.f;
        #pragma unroll
        for (int j = 0; j < 8; ++j) {
            float x = qs[h * PAD + p + 16 * j]; sq += x * x;
            float y = ks[h * PAD + p + 16 * j]; sk += y * y;
        }
        #pragma unroll
        for (int m = 1; m < 16; m <<= 1) {
            sq += __shfl_xor(sq, m);
            sk += __shfl_xor(sk, m);
        }
        if (p == 0) { rq[h] = rsqrtf(sq); rk[h] = rsqrtf(sk); }
    }
    __syncthreads();

    {
        int h = tid >> 4, g = tid & 15;
        float dot = 0.f;
        #pragma unroll
        for (int d = 0; d < HD; d += 4) {
            float4 q4 = *(const float4*)&qs[h * PAD + d];
            float4 k4 = *(const float4*)&ks[g * PAD + d];
            dot += q4.x * k4.x + q4.y * k4.y + q4.z * k4.z + q4.w * k4.w;
        }
        sm[h * 17 + g] = dot * rq[h] * rk[g] * (1.0f / 128.0f);
    }
    __syncthreads();

    {
        int h = tid & 15, u = tid >> 4;
        float o[8] = {};
        #pragma unroll
        for (int g = 0; g < 16; ++g) {
            float s = sm[h * 17 + g];
            #pragma unroll
            for (int i = 0; i < 8; ++i)
                o[i] = fmaf(s, vs[g * PAD + u + 16 * i], o[i]);
        }
        #pragma unroll
        for (int i = 0; i < 8; ++i)
            ot[(size_t)b * DDIM + u * 16 + 256 * i + h] = f2bf(o[i]);
    }
}

// ---------- in-place row LayerNorm ----------
__global__ __launch_bounds__(256)
void lnorm(float* __restrict__ x, const float* __restrict__ gamma, const float* __restrict__ beta)
{
    const int row = blockIdx.x;
    const int tid = threadIdx.x;
    float* xr = x + (size_t)row * DDIM;

    float4 v0 = *(const float4*)(xr + tid * 4);
    float4 v1 = *(const float4*)(xr + 1024 + tid * 4);
    float s  = v0.x + v0.y + v0.z + v0.w + v1.x + v1.y + v1.z + v1.w;
    float s2 = v0.x*v0.x + v0.y*v0.y + v0.z*v0.z + v0.w*v0.w
             + v1.x*v1.x + v1.y*v1.y + v1.z*v1.z + v1.w*v1.w;

    #pragma unroll
    for (int m = 1; m < 64; m <<= 1) {
        s  += __shfl_xor(s, m);
        s2 += __shfl_xor(s2, m);
    }
    __shared__ float ws1[4], ws2[4];
    if ((tid & 63) == 0) { ws1[tid >> 6] = s; ws2[tid >> 6] = s2; }
    __syncthreads();
    s  = ws1[0] + ws1[1] + ws1[2] + ws1[3];
    s2 = ws2[0] + ws2[1] + ws2[2] + ws2[3];

    const float mu  = s * (1.0f / DDIM);
    const float var = s2 * (1.0f / DDIM) - mu * mu;
    const float rstd = rsqrtf(var + 1e-5f);

    float4 g0 = *(const float4*)(gamma + tid * 4);
    float4 g1 = *(const float4*)(gamma + 1024 + tid * 4);
    float4 b0 = *(const float4*)(beta + tid * 4);
    float4 b1 = *(const float4*)(beta + 1024 + tid * 4);

    v0.x = (v0.x - mu) * rstd * g0.x + b0.x;
    v0.y = (v0.y - mu) * rstd * g0.y + b0.y;
    v0.z = (v0.z - mu) * rstd * g0.z + b0.z;
    v0.w = (v0.w - mu) * rstd * g0.w + b0.w;
    v1.x = (v1.x - mu) * rstd * g1.x + b1.x;
    v1.y = (v1.y - mu) * rstd * g1.y + b1.y;
    v1.z = (v1.z - mu) * rstd * g1.z + b1.z;
    v1.w = (v1.w - mu) * rstd * g1.w + b1.w;

    *(float4*)(xr + tid * 4) = v0;
    *(float4*)(xr + 1024 + tid * 4) = v1;
}

// ---------- launch ----------
extern "C" void kernel_launch(void* const* d_in, const int* in_sizes, int n_in,
                              void* d_out, int out_size, void* d_ws, size_t ws_size,
                              hipStream_t stream)
{
    const float* q     = (const float*)d_in[0];
    const float* k     = (const float*)d_in[1];
    const float* v     = (const float*)d_in[2];
    const float* Wq    = (const float*)d_in[3];
    const float* bq    = (const float*)d_in[4];
    const float* Wk    = (const float*)d_in[5];
    const float* bk    = (const float*)d_in[6];
    const float* Wv    = (const float*)d_in[7];
    const float* bv    = (const float*)d_in[8];
    const float* Wo    = (const float*)d_in[9];
    const float* bo    = (const float*)d_in[10];
    const float* gamma = (const float*)d_in[11];
    const float* beta  = (const float*)d_in[12];

    const size_t BD = (size_t)BDIM * DDIM;
    char* ws = (char*)d_ws;
    size_t off = 0;
    auto alloc = [&](size_t bytes) { void* p = ws + off; off += (bytes + 255) & ~(size_t)255; return p; };

    short* Wqt = (short*)alloc((size_t)DDIM * DDIM * 2);
    short* Wkt = (short*)alloc((size_t)DDIM * DDIM * 2);
    short* Wvt = (short*)alloc((size_t)DDIM * DDIM * 2);
    short* Wot = (short*)alloc((size_t)DDIM * DDIM * 2);
    short* xb  = (short*)alloc(BD * 2);   // bf16 conv buffer (q/k/v in turn), then attn out
    short* qpb = (short*)alloc(BD * 2);   // bf16 q-projection (attn input + residual)
    short* kpb = (short*)alloc(BD * 2);
    short* vpb = (short*)alloc(BD * 2);
    float* xout = (float*)d_out;

    wtrans<<<dim3(DDIM / 32, DDIM / 32, 4), dim3(32, 8), 0, stream>>>(Wq, Wk, Wv, Wo, Wqt, Wkt, Wvt, Wot);

    const int grid = (BDIM / 256) * (DDIM / 256);   // 1024
    const int n8 = (int)(BD / 8);

    cvt1<<<4096, 256, 0, stream>>>(q, xb, n8);
    gemm8<0><<<grid, 512, 0, stream>>>(xb, Wqt, bq, nullptr, qpb, nullptr);
    cvt1<<<4096, 256, 0, stream>>>(k, xb, n8);
    gemm8<0><<<grid, 512, 0, stream>>>(xb, Wkt, bk, nullptr, kpb, nullptr);
    cvt1<<<4096, 256, 0, stream>>>(v, xb, n8);
    gemm8<0><<<grid, 512, 0, stream>>>(xb, Wvt, bv, nullptr, vpb, nullptr);

    attn<<<BDIM, 256, 0, stream>>>(qpb, kpb, vpb, xb);

    gemm8<1><<<grid, 512, 0, stream>>>(xb, Wot, bo, qpb, nullptr, xout);

    lnorm<<<BDIM, 256, 0, stream>>>(xout, gamma, beta);
}